// Round 4
// baseline (177.029 us; speedup 1.0000x reference)
//
#include <hip/hip_runtime.h>
#include <hip/hip_bf16.h>

namespace {

constexpr int Sseq = 2048;
constexpr int NH   = 16;
constexpr int HD   = 64;
constexpr int ROW  = NH * HD;      // 1024 floats between consecutive s
constexpr int BM   = 64;           // q rows per block (1 m-tile per wave)
constexpr int BN   = 64;           // kv rows per tile
constexpr int NT   = Sseq / BN;    // 32 kv tiles
constexpr float QSCALE = 0.18033688011112042f; // (1/8) * log2(e)

typedef __bf16 bf16_t;
typedef __attribute__((ext_vector_type(8))) bf16_t bf16x8;
typedef __attribute__((ext_vector_type(4))) float f32x4;
typedef __attribute__((ext_vector_type(2))) unsigned int u32x2;
typedef __attribute__((ext_vector_type(4))) unsigned int u32x4;

union Frag { bf16x8 v; unsigned int u[4]; };

__device__ inline unsigned int pkbf(float a, float b) {
  union { __hip_bfloat162 h; unsigned int u; } x;
  x.h = __float22bfloat162_rn(make_float2(a, b));
  return x.u;
}

// mfma_f32_16x16x32_bf16: A[m=lane&15][k=quad*8+j], B[k=quad*8+j][n=lane&15],
// C/D: col=lane&15, row=quad*4+reg.
// S^T = K·Q^T (softmax state = lane scalar), O^T = V^T·P^T.
// LDS rows are 128B, 16B-chunk XOR swizzle (chunk ^= row&7).
//
// R4: R3 was latency-bound with grid-capped occupancy (512 blocks = 2
// blocks/CU, Occ 17.9%). Per-wave work is now lean (K/V staged in LDS), so
// BM 128->64 (MT 2->1) doubles grid to 1024 -> 4 blocks/CU (LDS 40KB,
// 4x40=160KB exact), 4 waves/SIMD to hide the per-tile dependency chain.

__global__ __launch_bounds__(256)
void fa_fwd(const float* __restrict__ Q, const float* __restrict__ K,
            const float* __restrict__ V, float* __restrict__ O) {
  const int id   = blockIdx.x;
  const int bh   = id & 31;           // b*16 + h ; XCD = id % 8
  const int qblk = id >> 5;
  const int tid  = threadIdx.x;
  const int wave = tid >> 6;
  const int lane = tid & 63;
  const int qd   = lane >> 4;         // quad
  const int lm   = lane & 15;

  const size_t base = (size_t)(bh >> 4) * Sseq * ROW + (size_t)(bh & 15) * HD;
  const float* qb = Q + base;
  const float* kb = K + base;
  const float* vb = V + base;
  float*       ob = O + base;

  __shared__ __align__(16) unsigned short KT[2][HD * 64];  // K [kv][d] bf16 dbuf 16KB
  __shared__ __align__(16) unsigned short VT[2][HD * 64];  // V^T [d][kv] bf16 dbuf 16KB
  __shared__ __align__(16) unsigned short PB[4][16 * 64];  // per-wave P 8KB

  const int qrow0 = qblk * BM + wave * 16;

  // Q B-fragments, pre-scaled by (1/sqrt(D))*log2(e) so p = exp2(s)
  Frag qf[2];
  {
    const float* qp = qb + (size_t)(qrow0 + lm) * ROW;
    for (int ks = 0; ks < 2; ++ks) {
      f32x4 a = *(const f32x4*)(qp + ks * 32 + qd * 8);
      f32x4 c = *(const f32x4*)(qp + ks * 32 + qd * 8 + 4);
      qf[ks].u[0] = pkbf(a[0] * QSCALE, a[1] * QSCALE);
      qf[ks].u[1] = pkbf(a[2] * QSCALE, a[3] * QSCALE);
      qf[ks].u[2] = pkbf(c[0] * QSCALE, c[1] * QSCALE);
      qf[ks].u[3] = pkbf(c[2] * QSCALE, c[3] * QSCALE);
    }
  }

  f32x4 oacc[4] = {};
  float lsum = 0.f;

  // staging assignments
  const int kr = tid >> 2;            // K: row kr, d = kd..kd+15
  const int kd = (tid & 3) * 16;
  const int n4 = (tid & 15) * 4;      // V: 4 kv-rows x 4 d-cols (transposed store)
  const int d4 = (tid >> 4) * 4;

  const float* kp = kb + (size_t)kr * ROW + kd;
  const float* vp = vb + (size_t)n4 * ROW + d4;

  // prologue: prefetch tile 0 into registers
  f32x4 kx0 = *(const f32x4*)(kp);
  f32x4 kx1 = *(const f32x4*)(kp + 4);
  f32x4 kx2 = *(const f32x4*)(kp + 8);
  f32x4 kx3 = *(const f32x4*)(kp + 12);
  f32x4 vx0 = *(const f32x4*)(vp);
  f32x4 vx1 = *(const f32x4*)(vp + ROW);
  f32x4 vx2 = *(const f32x4*)(vp + 2 * ROW);
  f32x4 vx3 = *(const f32x4*)(vp + 3 * ROW);

  for (int t = 0; t < NT; ++t) {
    unsigned short* kt = KT[t & 1];
    unsigned short* vt = VT[t & 1];

    { // stage K [kv][d] bf16, swizzled: two b128 writes
      int c0 = ((tid & 3) * 2) ^ (kr & 7);
      int c1 = ((tid & 3) * 2 + 1) ^ (kr & 7);
      u32x4 w0, w1;
      w0.x = pkbf(kx0[0], kx0[1]); w0.y = pkbf(kx0[2], kx0[3]);
      w0.z = pkbf(kx1[0], kx1[1]); w0.w = pkbf(kx1[2], kx1[3]);
      w1.x = pkbf(kx2[0], kx2[1]); w1.y = pkbf(kx2[2], kx2[3]);
      w1.z = pkbf(kx3[0], kx3[1]); w1.w = pkbf(kx3[2], kx3[3]);
      *(u32x4*)(kt + kr * 64 + c0 * 8) = w0;
      *(u32x4*)(kt + kr * 64 + c1 * 8) = w1;
    }
    { // stage V^T bf16, swizzled
      #pragma unroll
      for (int i = 0; i < 4; ++i) {
        int d = d4 + i;
        int chunk = (n4 >> 3) ^ (d & 7);
        u32x2 val; val.x = pkbf(vx0[i], vx1[i]); val.y = pkbf(vx2[i], vx3[i]);
        *(u32x2*)(vt + d * 64 + chunk * 8 + (n4 & 7)) = val;
      }
    }

    __syncthreads();  // buf (t&1) staged; dbuf -> single barrier per tile

    // issue global prefetch of tile t+1 (latency covered by compute below)
    if (t + 1 < NT) {
      kp += BN * ROW; vp += BN * ROW;
      kx0 = *(const f32x4*)(kp);
      kx1 = *(const f32x4*)(kp + 4);
      kx2 = *(const f32x4*)(kp + 8);
      kx3 = *(const f32x4*)(kp + 12);
      vx0 = *(const f32x4*)(vp);
      vx1 = *(const f32x4*)(vp + ROW);
      vx2 = *(const f32x4*)(vp + 2 * ROW);
      vx3 = *(const f32x4*)(vp + 3 * ROW);
    }

    // S^T = K·Q^T ; P = exp2(S^T) -> LDS (K frags from LDS)
    #pragma unroll
    for (int c = 0; c < 4; ++c) {
      Frag kf0, kf1;
      {
        int r = c * 16 + lm;
        int ch0 = (qd) ^ (lm & 7);
        int ch1 = (4 + qd) ^ (lm & 7);
        kf0.v = *(const bf16x8*)(kt + r * 64 + ch0 * 8);
        kf1.v = *(const bf16x8*)(kt + r * 64 + ch1 * 8);
      }
      f32x4 s = {};
      s = __builtin_amdgcn_mfma_f32_16x16x32_bf16(kf0.v, qf[0].v, s, 0, 0, 0);
      s = __builtin_amdgcn_mfma_f32_16x16x32_bf16(kf1.v, qf[1].v, s, 0, 0, 0);
      float e0 = __builtin_amdgcn_exp2f(s[0]);
      float e1 = __builtin_amdgcn_exp2f(s[1]);
      float e2 = __builtin_amdgcn_exp2f(s[2]);
      float e3 = __builtin_amdgcn_exp2f(s[3]);
      lsum += (e0 + e1) + (e2 + e3);
      int n = c * 16 + qd * 4;              // rows of S^T this lane holds
      int chunk = (n >> 3) ^ (lm & 7);
      u32x2 val; val.x = pkbf(e0, e1); val.y = pkbf(e2, e3);
      *(u32x2*)(PB[wave] + lm * 64 + chunk * 8 + (n & 7)) = val;
    }

    __threadfence_block();  // order P writes vs typed re-reads (same wave)

    // O^T += V^T · P^T
    #pragma unroll
    for (int ks = 0; ks < 2; ++ks) {
      bf16x8 pfr;
      {
        int chunk = (ks * 4 + qd) ^ (lm & 7);
        pfr = *(const bf16x8*)(PB[wave] + lm * 64 + chunk * 8);
      }
      #pragma unroll
      for (int dt = 0; dt < 4; ++dt) {
        int d = dt * 16 + lm;
        int chunk = (ks * 4 + qd) ^ (d & 7);
        bf16x8 vf = *(const bf16x8*)(vt + d * 64 + chunk * 8);
        oacc[dt] = __builtin_amdgcn_mfma_f32_16x16x32_bf16(vf, pfr, oacc[dt], 0, 0, 0);
      }
    }
  }

  // epilogue: l = sum over quads, normalize, coalesced f32x4 stores
  {
    float l = lsum;
    l += __shfl_xor(l, 16, 64);
    l += __shfl_xor(l, 32, 64);
    float r = 1.0f / l;
    float* op = ob + (size_t)(qrow0 + lm) * ROW + qd * 4;
    #pragma unroll
    for (int dt = 0; dt < 4; ++dt) {
      f32x4 o = oacc[dt];
      o[0] *= r; o[1] *= r; o[2] *= r; o[3] *= r;
      *(f32x4*)(op + dt * 16) = o;
    }
  }
}

} // namespace

extern "C" void kernel_launch(void* const* d_in, const int* in_sizes, int n_in,
                              void* d_out, int out_size, void* d_ws, size_t ws_size,
                              hipStream_t stream) {
  const float* q = (const float*)d_in[0];
  const float* k = (const float*)d_in[1];
  const float* v = (const float*)d_in[2];
  float* o = (float*)d_out;
  (void)in_sizes; (void)n_in; (void)out_size; (void)d_ws; (void)ws_size;
  dim3 grid(2 * NH * (Sseq / BM));  // 1024 blocks: id = qblk*32 + (b*16+h)
  dim3 block(256);
  hipLaunchKernelGGL(fa_fwd, grid, block, 0, stream, q, k, v, o);
}

// Round 5
// 140.963 us; speedup vs baseline: 1.2559x; 1.2559x over previous
//
#include <hip/hip_runtime.h>
#include <hip/hip_bf16.h>

namespace {

constexpr int Sseq = 2048;
constexpr int NH   = 16;
constexpr int HD   = 64;
constexpr int ROW  = NH * HD;      // 1024 floats between consecutive s
constexpr int BM   = 128;          // q rows per block
constexpr int BN   = 64;           // kv rows per tile
constexpr int MT   = 2;            // 16-row m-tiles per wave
constexpr int NT   = Sseq / BN;    // 32 kv tiles (even)
constexpr float QSCALE = 0.18033688011112042f; // (1/8) * log2(e)

typedef __bf16 bf16_t;
typedef __attribute__((ext_vector_type(8))) bf16_t bf16x8;
typedef __attribute__((ext_vector_type(4))) float f32x4;
typedef __attribute__((ext_vector_type(2))) unsigned int u32x2;
typedef __attribute__((ext_vector_type(4))) unsigned int u32x4;

union Frag { bf16x8 v; unsigned int u[4]; };

__device__ inline unsigned int pkbf(float a, float b) {
  union { __hip_bfloat162 h; unsigned int u; } x;
  x.h = __float22bfloat162_rn(make_float2(a, b));
  return x.u;
}

// mfma_f32_16x16x32_bf16: A[m=lane&15][k=quad*8+j], B[k=quad*8+j][n=lane&15],
// C/D: col=lane&15, row=quad*4+reg.
// S^T = K·Q^T (softmax state = lane scalar), O^T = V^T·P^T.
// LDS rows are 128B, 16B-chunk XOR swizzle (chunk ^= row&7).
//
// R5: R3 structure (BM=128, grid 512 — best so far; R2/R4 proved occupancy
// bought by multiplying total work is a net loss). New: prefetch distance 2.
// R3's register prefetch of t+1 had only one compute phase (~500 cyc) to
// cover ~900-cyc HBM latency -> every wave stalled on vmcnt at the staging
// cvt, every tile. Two register sets, 2x-unrolled tile loop: loads for t+2
// issued right after barrier(t) -> ~2 compute phases of cover.

__global__ __launch_bounds__(256)
void fa_fwd(const float* __restrict__ Q, const float* __restrict__ K,
            const float* __restrict__ V, float* __restrict__ O) {
  const int id   = blockIdx.x;
  const int bh   = id & 31;           // b*16 + h ; XCD = id % 8
  const int qblk = id >> 5;
  const int tid  = threadIdx.x;
  const int wave = tid >> 6;
  const int lane = tid & 63;
  const int qd   = lane >> 4;         // quad
  const int lm   = lane & 15;

  const size_t base = (size_t)(bh >> 4) * Sseq * ROW + (size_t)(bh & 15) * HD;
  const float* qb = Q + base;
  const float* kb = K + base;
  const float* vb = V + base;
  float*       ob = O + base;

  __shared__ __align__(16) unsigned short KT[2][HD * 64];     // K [kv][d] bf16 16KB
  __shared__ __align__(16) unsigned short VT[2][HD * 64];     // V^T [d][kv] bf16 16KB
  __shared__ __align__(16) unsigned short PB[4][MT][16 * 64]; // per-wave P 16KB

  const int qrow0 = qblk * BM + wave * (MT * 16);

  // Q B-fragments, pre-scaled by (1/sqrt(D))*log2(e) so p = exp2(s)
  Frag qf[MT][2];
  for (int mt = 0; mt < MT; ++mt) {
    const float* qp = qb + (size_t)(qrow0 + mt * 16 + lm) * ROW;
    for (int ks = 0; ks < 2; ++ks) {
      f32x4 a = *(const f32x4*)(qp + ks * 32 + qd * 8);
      f32x4 c = *(const f32x4*)(qp + ks * 32 + qd * 8 + 4);
      qf[mt][ks].u[0] = pkbf(a[0] * QSCALE, a[1] * QSCALE);
      qf[mt][ks].u[1] = pkbf(a[2] * QSCALE, a[3] * QSCALE);
      qf[mt][ks].u[2] = pkbf(c[0] * QSCALE, c[1] * QSCALE);
      qf[mt][ks].u[3] = pkbf(c[2] * QSCALE, c[3] * QSCALE);
    }
  }

  f32x4 oacc[MT][4] = {};
  float lsum[MT] = {};

  // staging assignments
  const int kr = tid >> 2;            // K: row kr, d = kd..kd+15
  const int kd = (tid & 3) * 16;
  const int n4 = (tid & 15) * 4;      // V: 4 kv-rows x 4 d-cols (transposed store)
  const int d4 = (tid >> 4) * 4;

  const float* kpA = kb + (size_t)kr * ROW + kd;          // tiles 0,2,4,...
  const float* vpA = vb + (size_t)n4 * ROW + d4;
  const float* kpB = kpA + (size_t)BN * ROW;              // tiles 1,3,5,...
  const float* vpB = vpA + (size_t)BN * ROW;

  f32x4 ka[4], va[4], kB[4], vB[4];

  auto ldK = [&](const float* p, f32x4* r) {
    r[0] = *(const f32x4*)(p);
    r[1] = *(const f32x4*)(p + 4);
    r[2] = *(const f32x4*)(p + 8);
    r[3] = *(const f32x4*)(p + 12);
  };
  auto ldV = [&](const float* p, f32x4* r) {
    r[0] = *(const f32x4*)(p);
    r[1] = *(const f32x4*)(p + ROW);
    r[2] = *(const f32x4*)(p + 2 * ROW);
    r[3] = *(const f32x4*)(p + 3 * ROW);
  };

  auto stage = [&](unsigned short* kt, unsigned short* vt,
                   const f32x4* kx, const f32x4* vx) {
    { // K [kv][d] bf16, swizzled: two b128 writes
      int c0 = ((tid & 3) * 2) ^ (kr & 7);
      int c1 = ((tid & 3) * 2 + 1) ^ (kr & 7);
      u32x4 w0, w1;
      w0.x = pkbf(kx[0][0], kx[0][1]); w0.y = pkbf(kx[0][2], kx[0][3]);
      w0.z = pkbf(kx[1][0], kx[1][1]); w0.w = pkbf(kx[1][2], kx[1][3]);
      w1.x = pkbf(kx[2][0], kx[2][1]); w1.y = pkbf(kx[2][2], kx[2][3]);
      w1.z = pkbf(kx[3][0], kx[3][1]); w1.w = pkbf(kx[3][2], kx[3][3]);
      *(u32x4*)(kt + kr * 64 + c0 * 8) = w0;
      *(u32x4*)(kt + kr * 64 + c1 * 8) = w1;
    }
    { // V^T bf16, swizzled
      #pragma unroll
      for (int i = 0; i < 4; ++i) {
        int d = d4 + i;
        int chunk = (n4 >> 3) ^ (d & 7);
        u32x2 val; val.x = pkbf(vx[0][i], vx[1][i]); val.y = pkbf(vx[2][i], vx[3][i]);
        *(u32x2*)(vt + d * 64 + chunk * 8 + (n4 & 7)) = val;
      }
    }
  };

  auto compute = [&](const unsigned short* kt, const unsigned short* vt) {
    // S^T = K·Q^T ; P = exp2(S^T) -> LDS (K frags from LDS, reused over mt)
    #pragma unroll
    for (int c = 0; c < 4; ++c) {
      Frag kf0, kf1;
      {
        int r = c * 16 + lm;
        int ch0 = (qd) ^ (lm & 7);
        int ch1 = (4 + qd) ^ (lm & 7);
        kf0.v = *(const bf16x8*)(kt + r * 64 + ch0 * 8);
        kf1.v = *(const bf16x8*)(kt + r * 64 + ch1 * 8);
      }
      #pragma unroll
      for (int mt = 0; mt < MT; ++mt) {
        f32x4 s = {};
        s = __builtin_amdgcn_mfma_f32_16x16x32_bf16(kf0.v, qf[mt][0].v, s, 0, 0, 0);
        s = __builtin_amdgcn_mfma_f32_16x16x32_bf16(kf1.v, qf[mt][1].v, s, 0, 0, 0);
        float e0 = __builtin_amdgcn_exp2f(s[0]);
        float e1 = __builtin_amdgcn_exp2f(s[1]);
        float e2 = __builtin_amdgcn_exp2f(s[2]);
        float e3 = __builtin_amdgcn_exp2f(s[3]);
        lsum[mt] += (e0 + e1) + (e2 + e3);
        int n = c * 16 + qd * 4;              // rows of S^T this lane holds
        int chunk = (n >> 3) ^ (lm & 7);
        u32x2 val; val.x = pkbf(e0, e1); val.y = pkbf(e2, e3);
        *(u32x2*)(PB[wave][mt] + lm * 64 + chunk * 8 + (n & 7)) = val;
      }
    }

    __threadfence_block();  // order P writes vs typed re-reads (same wave)

    // O^T += V^T · P^T
    #pragma unroll
    for (int ks = 0; ks < 2; ++ks) {
      bf16x8 pfr[MT];
      #pragma unroll
      for (int mt = 0; mt < MT; ++mt) {
        int chunk = (ks * 4 + qd) ^ (lm & 7);
        pfr[mt] = *(const bf16x8*)(PB[wave][mt] + lm * 64 + chunk * 8);
      }
      #pragma unroll
      for (int dt = 0; dt < 4; ++dt) {
        int d = dt * 16 + lm;
        int chunk = (ks * 4 + qd) ^ (d & 7);
        bf16x8 vf = *(const bf16x8*)(vt + d * 64 + chunk * 8);
        #pragma unroll
        for (int mt = 0; mt < MT; ++mt)
          oacc[mt][dt] = __builtin_amdgcn_mfma_f32_16x16x32_bf16(vf, pfr[mt], oacc[mt][dt], 0, 0, 0);
      }
    }
  };

  // prologue: prefetch tiles 0 (set A) and 1 (set B)
  ldK(kpA, ka); ldV(vpA, va);
  ldK(kpB, kB); ldV(vpB, vB);

  for (int t = 0; t < NT; t += 2) {
    // ---- tile t (buffer 0, reg set A)
    stage(KT[0], VT[0], ka, va);
    __syncthreads();
    if (t + 2 < NT) {   // issue loads for tile t+2 (2 compute phases of cover)
      kpA += (size_t)2 * BN * ROW; vpA += (size_t)2 * BN * ROW;
      ldK(kpA, ka); ldV(vpA, va);
    }
    compute(KT[0], VT[0]);

    // ---- tile t+1 (buffer 1, reg set B)
    stage(KT[1], VT[1], kB, vB);
    __syncthreads();
    if (t + 3 < NT) {   // issue loads for tile t+3
      kpB += (size_t)2 * BN * ROW; vpB += (size_t)2 * BN * ROW;
      ldK(kpB, kB); ldV(vpB, vB);
    }
    compute(KT[1], VT[1]);
  }

  // epilogue: l = sum over quads, normalize, coalesced f32x4 stores
  #pragma unroll
  for (int mt = 0; mt < MT; ++mt) {
    float l = lsum[mt];
    l += __shfl_xor(l, 16, 64);
    l += __shfl_xor(l, 32, 64);
    float r = 1.0f / l;
    float* op = ob + (size_t)(qrow0 + mt * 16 + lm) * ROW + qd * 4;
    #pragma unroll
    for (int dt = 0; dt < 4; ++dt) {
      f32x4 o = oacc[mt][dt];
      o[0] *= r; o[1] *= r; o[2] *= r; o[3] *= r;
      *(f32x4*)(op + dt * 16) = o;
    }
  }
}

} // namespace

extern "C" void kernel_launch(void* const* d_in, const int* in_sizes, int n_in,
                              void* d_out, int out_size, void* d_ws, size_t ws_size,
                              hipStream_t stream) {
  const float* q = (const float*)d_in[0];
  const float* k = (const float*)d_in[1];
  const float* v = (const float*)d_in[2];
  float* o = (float*)d_out;
  (void)in_sizes; (void)n_in; (void)out_size; (void)d_ws; (void)ws_size;
  dim3 grid(2 * NH * (Sseq / BM));  // 512 blocks: id = qblk*32 + (b*16+h)
  dim3 block(256);
  hipLaunchKernelGGL(fa_fwd, grid, block, 0, stream, q, k, v, o);
}